// Round 2
// baseline (666.299 us; speedup 1.0000x reference)
//
#include <hip/hip_runtime.h>

// Problem constants (from reference):
//   D = 8388608 elements, N = M = 1024 (power of two -> mod == AND)
// Outputs concatenated in d_out (float32):
//   [0,      D)      phase_out  (as float)
//   [D,     2D)      mag_out    (as float)
//   [2D,    3D)      signal
//   [3D]             strength   (scalar)
//   [3D+1,  4D+1)    grad_phase   <- base misaligned by 1 float, scalar stores
//   [4D+1,  5D+1)    grad_mag     <- same
//
// Fused single-kernel design: per-block partial sums -> d_ws, last block to
// finish (device-scope atomic counter) reduces the partials and writes
// out[3D]. Reduction order is identical to the previous two-pass version
// (stride-BLOCK accumulation + 64-lane shuffle tree) -> bit-identical result.
constexpr int D_TOTAL = 8388608;
constexpr int TBL = 1024;
constexpr int IDX_MASK = 1023;
constexpr int BLOCK = 256;
constexpr int VEC = 4;                        // elements per thread
constexpr int ELEMS_PER_BLOCK = BLOCK * VEC;  // 1024
constexpr int NBLOCKS = D_TOTAL / ELEMS_PER_BLOCK;  // 8192

typedef float f32x4 __attribute__((ext_vector_type(4)));
typedef int   i32x4 __attribute__((ext_vector_type(4)));

__global__ __launch_bounds__(BLOCK) void phasecell_fused(
    const int* __restrict__ ctx_p, const int* __restrict__ ctx_m,
    const int* __restrict__ self_p, const int* __restrict__ self_m,
    const float* __restrict__ cos_t, const float* __restrict__ exp_t,
    const float* __restrict__ dcos_t, const float* __restrict__ dexp_t,
    float* __restrict__ out, float* __restrict__ partials,
    unsigned int* __restrict__ counter) {
  // Stage interleaved tables in LDS: one ds_read_b64 per gather.
  __shared__ float2 s_phase[TBL];  // (cos, dcos)
  __shared__ float2 s_mag[TBL];    // (exp, dexp)
  for (int i = threadIdx.x; i < TBL; i += BLOCK) {
    s_phase[i] = make_float2(cos_t[i], dcos_t[i]);
    s_mag[i]   = make_float2(exp_t[i], dexp_t[i]);
  }
  __syncthreads();

  const int base = (blockIdx.x * BLOCK + threadIdx.x) * VEC;

  // Streaming data, zero reuse -> nontemporal loads/stores (nt bit).
  const i32x4 cp = __builtin_nontemporal_load((const i32x4*)(ctx_p + base));
  const i32x4 cm = __builtin_nontemporal_load((const i32x4*)(ctx_m + base));
  const i32x4 sp = __builtin_nontemporal_load((const i32x4*)(self_p + base));
  const i32x4 sm = __builtin_nontemporal_load((const i32x4*)(self_m + base));

  int p[VEC], m[VEC];
#pragma unroll
  for (int j = 0; j < VEC; ++j) {
    p[j] = (cp[j] + sp[j]) & IDX_MASK;
    m[j] = (cm[j] + sm[j]) & IDX_MASK;
  }

  f32x4 po, mo, sig;
  float gph[VEC], gmg[VEC];
  float local = 0.f;
#pragma unroll
  for (int j = 0; j < VEC; ++j) {
    const float2 ph = s_phase[p[j]];
    const float2 mg = s_mag[m[j]];
    const float s = ph.x * mg.x;
    sig[j] = s;
    gph[j] = ph.y * mg.x;
    gmg[j] = ph.x * mg.y;
    po[j] = (float)p[j];
    mo[j] = (float)m[j];
    local += s;
  }

  // Aligned float4 stores (section bases 0, D, 2D are multiples of 4 floats).
  __builtin_nontemporal_store(po,  (f32x4*)(out + base));
  __builtin_nontemporal_store(mo,  (f32x4*)(out + D_TOTAL + base));
  __builtin_nontemporal_store(sig, (f32x4*)(out + 2 * D_TOTAL + base));

  // Grad sections start at 3D+1 / 4D+1 -> 4B misaligned, scalar stores.
  // Write-combining in L2 merges adjacent waves' spans into full lines, so
  // this costs ~6 extra VMEM instrs/wave (~1.3 us total), not HBM bytes.
  float* gp_base = out + 3 * D_TOTAL + 1 + base;
  float* gm_base = out + 4 * D_TOTAL + 1 + base;
#pragma unroll
  for (int j = 0; j < VEC; ++j) {
    __builtin_nontemporal_store(gph[j], gp_base + j);
    __builtin_nontemporal_store(gmg[j], gm_base + j);
  }

  // Block reduction of `local` -> partials[blockIdx.x] (deterministic).
#pragma unroll
  for (int off = 32; off > 0; off >>= 1) local += __shfl_down(local, off, 64);
  __shared__ float wsum[BLOCK / 64];
  const int wave = threadIdx.x >> 6;
  const int lane = threadIdx.x & 63;
  if (lane == 0) wsum[wave] = local;
  __syncthreads();
  if (threadIdx.x == 0) {
    float t = 0.f;
#pragma unroll
    for (int w = 0; w < BLOCK / 64; ++w) t += wsum[w];
    partials[blockIdx.x] = t;
  }

  // Last-block-done: the final block to increment the counter reduces all
  // partials. Device-scope fences handle cross-XCD visibility (G16).
  __shared__ bool s_last;
  if (threadIdx.x == 0) {
    __threadfence();  // release: make partials[blockIdx.x] visible
    unsigned int prev = atomicAdd(counter, 1u);  // device-scope by default
    s_last = (prev == NBLOCKS - 1);
  }
  __syncthreads();
  if (s_last) {  // block-uniform branch; __syncthreads inside is safe
    __threadfence();  // acquire: see all blocks' partials
    float s = 0.f;
    for (int i = threadIdx.x; i < NBLOCKS; i += BLOCK) s += partials[i];
#pragma unroll
    for (int off = 32; off > 0; off >>= 1) s += __shfl_down(s, off, 64);
    if (lane == 0) wsum[wave] = s;
    __syncthreads();
    if (threadIdx.x == 0) {
      float t = 0.f;
#pragma unroll
      for (int w = 0; w < BLOCK / 64; ++w) t += wsum[w];
      out[3 * (size_t)D_TOTAL] = t;  // strength
    }
  }
}

extern "C" void kernel_launch(void* const* d_in, const int* in_sizes, int n_in,
                              void* d_out, int out_size, void* d_ws, size_t ws_size,
                              hipStream_t stream) {
  const int* ctx_p  = (const int*)d_in[0];
  const int* ctx_m  = (const int*)d_in[1];
  const int* self_p = (const int*)d_in[2];
  const int* self_m = (const int*)d_in[3];
  const float* cos_t  = (const float*)d_in[4];
  const float* exp_t  = (const float*)d_in[5];
  const float* dcos_t = (const float*)d_in[6];
  const float* dexp_t = (const float*)d_in[7];
  float* out = (float*)d_out;
  float* partials = (float*)d_ws;                       // NBLOCKS floats = 32 KB
  unsigned int* counter = (unsigned int*)((char*)d_ws + NBLOCKS * sizeof(float));

  // d_ws is re-poisoned to 0xAA before every launch -> zero the counter.
  // hipMemsetAsync on `stream` is graph-capture safe.
  hipMemsetAsync(counter, 0, sizeof(unsigned int), stream);

  phasecell_fused<<<NBLOCKS, BLOCK, 0, stream>>>(
      ctx_p, ctx_m, self_p, self_m, cos_t, exp_t, dcos_t, dexp_t,
      out, partials, counter);
}

// Round 3
// 290.453 us; speedup vs baseline: 2.2940x; 2.2940x over previous
//
#include <hip/hip_runtime.h>

// Problem constants (from reference):
//   D = 8388608 elements, N = M = 1024 (power of two -> mod == AND)
// Outputs concatenated in d_out (float32):
//   [0,      D)      phase_out  (as float)
//   [D,     2D)      mag_out    (as float)
//   [2D,    3D)      signal
//   [3D]             strength   (scalar)
//   [3D+1,  4D+1)    grad_phase   <- base misaligned by 4B
//   [4D+1,  5D+1)    grad_mag     <- same
//
// Two-kernel design (round-1 structure, restored): main kernel writes the 5
// streams + per-block partial sums to d_ws; a 1-block kernel reduces the
// partials. Round 2's fused last-block-done pattern regressed 5x: 8192
// device-scope atomicAdds on one cache line across 8 XCDs serialized at
// ~55ns each (~456us measured at 6.5% HBM BW / 1.7% VALU). Never again.
constexpr int D_TOTAL = 8388608;
constexpr int TBL = 1024;
constexpr int IDX_MASK = 1023;
constexpr int BLOCK = 256;
constexpr int VEC = 8;                        // elements per thread
constexpr int ELEMS_PER_BLOCK = BLOCK * VEC;  // 2048
constexpr int NBLOCKS = D_TOTAL / ELEMS_PER_BLOCK;  // 4096

typedef float f32x4 __attribute__((ext_vector_type(4)));
typedef float f32x8 __attribute__((ext_vector_type(8)));
typedef int   i32x8 __attribute__((ext_vector_type(8)));
// 4-byte-aligned float4: grad sections start at 3D+1/4D+1 (4B off 16B).
// global_store_dwordx4 only needs dword alignment in HW; this typedef lets
// clang emit it instead of 4 scalar stores.
typedef f32x4 f32x4u __attribute__((aligned(4)));

__global__ __launch_bounds__(BLOCK) void phasecell_main(
    const int* __restrict__ ctx_p, const int* __restrict__ ctx_m,
    const int* __restrict__ self_p, const int* __restrict__ self_m,
    const float* __restrict__ cos_t, const float* __restrict__ exp_t,
    const float* __restrict__ dcos_t, const float* __restrict__ dexp_t,
    float* __restrict__ out, float* __restrict__ block_sums) {
  // Stage interleaved tables in LDS: one ds_read_b64 per gather.
  // (Measured r2: ~5 conflict-cycles/gather -> ~4us total. Not a bottleneck.)
  __shared__ float2 s_phase[TBL];  // (cos, dcos)
  __shared__ float2 s_mag[TBL];    // (exp, dexp)
  for (int i = threadIdx.x; i < TBL; i += BLOCK) {
    s_phase[i] = make_float2(cos_t[i], dcos_t[i]);
    s_mag[i]   = make_float2(exp_t[i], dexp_t[i]);
  }
  __syncthreads();

  const int base = (blockIdx.x * BLOCK + threadIdx.x) * VEC;

  const i32x8 cp = *reinterpret_cast<const i32x8*>(ctx_p + base);
  const i32x8 cm = *reinterpret_cast<const i32x8*>(ctx_m + base);
  const i32x8 sp = *reinterpret_cast<const i32x8*>(self_p + base);
  const i32x8 sm = *reinterpret_cast<const i32x8*>(self_m + base);

  int p[VEC], m[VEC];
#pragma unroll
  for (int j = 0; j < VEC; ++j) {
    p[j] = (cp[j] + sp[j]) & IDX_MASK;
    m[j] = (cm[j] + sm[j]) & IDX_MASK;
  }

  f32x8 po, mo, sig;
  f32x4 gph0, gph1, gmg0, gmg1;
  float local = 0.f;
#pragma unroll
  for (int j = 0; j < VEC; ++j) {
    const float2 ph = s_phase[p[j]];
    const float2 mg = s_mag[m[j]];
    const float s = ph.x * mg.x;
    sig[j] = s;
    const float gp = ph.y * mg.x;
    const float gm = ph.x * mg.y;
    if (j < 4) { gph0[j] = gp; gmg0[j] = gm; }
    else       { gph1[j - 4] = gp; gmg1[j - 4] = gm; }
    po[j] = (float)p[j];
    mo[j] = (float)m[j];
    local += s;
  }

  // 32B-aligned stores (section bases 0, D, 2D are multiples of 8 floats).
  *reinterpret_cast<f32x8*>(out + base)                = po;
  *reinterpret_cast<f32x8*>(out + D_TOTAL + base)      = mo;
  *reinterpret_cast<f32x8*>(out + 2 * D_TOTAL + base)  = sig;

  // Grad sections: 4B-aligned dwordx4 stores.
  float* gp_base = out + 3 * D_TOTAL + 1 + base;
  float* gm_base = out + 4 * D_TOTAL + 1 + base;
  *reinterpret_cast<f32x4u*>(gp_base)     = gph0;
  *reinterpret_cast<f32x4u*>(gp_base + 4) = gph1;
  *reinterpret_cast<f32x4u*>(gm_base)     = gmg0;
  *reinterpret_cast<f32x4u*>(gm_base + 4) = gmg1;

  // Block reduction of `local` -> block_sums[blockIdx.x] (deterministic).
#pragma unroll
  for (int off = 32; off > 0; off >>= 1) local += __shfl_down(local, off, 64);
  __shared__ float wsum[BLOCK / 64];
  const int wave = threadIdx.x >> 6;
  const int lane = threadIdx.x & 63;
  if (lane == 0) wsum[wave] = local;
  __syncthreads();
  if (threadIdx.x == 0) {
    float t = 0.f;
#pragma unroll
    for (int w = 0; w < BLOCK / 64; ++w) t += wsum[w];
    block_sums[blockIdx.x] = t;
  }
}

__global__ __launch_bounds__(BLOCK) void phasecell_reduce(
    const float* __restrict__ partials, float* __restrict__ strength_out) {
  float s = 0.f;
  for (int i = threadIdx.x; i < NBLOCKS; i += BLOCK) s += partials[i];
#pragma unroll
  for (int off = 32; off > 0; off >>= 1) s += __shfl_down(s, off, 64);
  __shared__ float wsum[BLOCK / 64];
  const int wave = threadIdx.x >> 6;
  const int lane = threadIdx.x & 63;
  if (lane == 0) wsum[wave] = s;
  __syncthreads();
  if (threadIdx.x == 0) {
    float t = 0.f;
#pragma unroll
    for (int w = 0; w < BLOCK / 64; ++w) t += wsum[w];
    strength_out[0] = t;  // out[3D]
  }
}

extern "C" void kernel_launch(void* const* d_in, const int* in_sizes, int n_in,
                              void* d_out, int out_size, void* d_ws, size_t ws_size,
                              hipStream_t stream) {
  const int* ctx_p  = (const int*)d_in[0];
  const int* ctx_m  = (const int*)d_in[1];
  const int* self_p = (const int*)d_in[2];
  const int* self_m = (const int*)d_in[3];
  const float* cos_t  = (const float*)d_in[4];
  const float* exp_t  = (const float*)d_in[5];
  const float* dcos_t = (const float*)d_in[6];
  const float* dexp_t = (const float*)d_in[7];
  float* out = (float*)d_out;
  float* block_sums = (float*)d_ws;  // NBLOCKS floats = 16 KB

  phasecell_main<<<NBLOCKS, BLOCK, 0, stream>>>(
      ctx_p, ctx_m, self_p, self_m, cos_t, exp_t, dcos_t, dexp_t, out, block_sums);
  phasecell_reduce<<<1, BLOCK, 0, stream>>>(block_sums, out + 3 * (size_t)D_TOTAL);
}